// Round 8
// baseline (749.058 us; speedup 1.0000x reference)
//
#include <hip/hip_runtime.h>
#include <hip/hip_bf16.h>

// ---------------- types ----------------
typedef unsigned short u16;
typedef u16   u16x4 __attribute__((ext_vector_type(4)));
typedef u16   u16x8 __attribute__((ext_vector_type(8)));
typedef short s16x8 __attribute__((ext_vector_type(8)));
typedef float f32x4 __attribute__((ext_vector_type(4)));
typedef float f32x16 __attribute__((ext_vector_type(16)));

// Problem constants
#define NB   64
#define NL   512
#define ND   512
#define NA   8
#define K2   1024        // 2*D
#define MROWS 32768      // B*L

__device__ __forceinline__ float b2f(u16 u) {
    unsigned int x = ((unsigned int)u) << 16;
    return __uint_as_float(x);
}
__device__ __forceinline__ u16 f2b(float f) {
    unsigned int x = __float_as_uint(f);
    unsigned int r = (x + 0x7fffu + ((x >> 16) & 1u)) >> 16;
    return (u16)r;
}

// permuted column for 32x32x16 bf16 A/B fragments: lane half h = l>>5 holds
// k = 4h + e0 + 8*e1 (e = e1*4+e0). Stored so each lane's 8 elems contiguous:
// pos = (k>>4)*16 + ((k>>2)&1)*8 + ((k>>3)&1)*4 + (k&3)
__device__ __forceinline__ int permc32(int k) {
    return ((k >> 4) << 4) + (((k >> 2) & 1) << 3) + (((k >> 3) & 1) << 2) + (k & 3);
}

__device__ __forceinline__ void gload16(const u16* g, u16* l) {
    __builtin_amdgcn_global_load_lds(
        (const __attribute__((address_space(1))) unsigned int*)g,
        (__attribute__((address_space(3))) unsigned int*)l, 16, 0, 0);
}

// ---------------- kernel 1: build permuted bf16 Batch [32768][1024] ----------------
__global__ void build_batch(const float* __restrict__ H, const float* __restrict__ U,
                            u16* __restrict__ Bt) {
    size_t stride = (size_t)gridDim.x * blockDim.x;
    for (size_t idx = (size_t)blockIdx.x * blockDim.x + threadIdx.x;
         idx < (size_t)MROWS * 256; idx += stride) {
        int r  = (int)(idx >> 8);
        int c  = ((int)idx & 255) << 2;       // permuted col (multiple of 4)
        int c16 = c & 15;
        int h  = (c16 >> 3) & 1;
        int e1 = (c16 >> 2) & 1;
        int kbase = ((c >> 4) << 4) + 4 * h + 8 * e1;   // 4 consecutive k
        const float* src;
        if (kbase < ND) src = H + (size_t)r * ND + kbase;
        else { int b = r >> 9; src = U + (size_t)b * ND + (kbase - ND); }
        f32x4 v = *(const f32x4*)src;
        u16x4 o;
        o[0] = f2b(v[0]); o[1] = f2b(v[1]); o[2] = f2b(v[2]); o[3] = f2b(v[3]);
        *(u16x4*)(Bt + (size_t)r * K2 + c) = o;
    }
}

// ---------------- kernel 2: W (A,1024,512) f32 -> Wt (A,512,1024) bf16 permuted ----------------
__global__ void build_wt(const float* __restrict__ Wmf, const float* __restrict__ Wpf,
                         u16* __restrict__ Wm, u16* __restrict__ Wp) {
    __shared__ float ld[32][65];
    int bid = blockIdx.x;
    int kt  = bid & 31;
    int dt  = (bid >> 5) & 7;
    int a   = (bid >> 8) & 7;
    int mat = bid >> 11;
    const float* W = mat ? Wpf : Wmf;
    u16* Wt = mat ? Wp : Wm;
    int k0 = kt * 32, d0 = dt * 64;
    int t = threadIdx.x;
    #pragma unroll
    for (int it = 0; it < 8; ++it) {
        int lin = it * 256 + t;
        int i = lin >> 6, j = lin & 63;
        ld[i][j] = W[((size_t)a * K2 + k0 + i) * ND + d0 + j];
    }
    __syncthreads();
    #pragma unroll
    for (int it = 0; it < 8; ++it) {
        int lin = it * 256 + t;
        int dl = lin >> 5, kl = lin & 31;
        int k = k0 + kl;
        Wt[((size_t)a * ND + d0 + dl) * K2 + permc32(k)] = f2b(ld[kl][dl]);
    }
}

// ---------------- kernel 3: 32x32x16 dual GEMM + gate + LDS-tiled epilogue ----------------
// BM=256, BN=128, BK=64, 8 waves (2M x 4N), double-buffered LDS, stage 1 ahead.
// One barrier + one vmcnt per K-step; 4 MFMA clusters of 8 x mfma_32x32x16.
#define BAR()    do { __builtin_amdgcn_sched_barrier(0); \
                      __builtin_amdgcn_s_barrier(); \
                      __builtin_amdgcn_sched_barrier(0); } while (0)
#define WAITV(n) do { asm volatile("s_waitcnt vmcnt(" #n ")" ::: "memory"); \
                      __builtin_amdgcn_sched_barrier(0); } while (0)
#define PRIO1    __builtin_amdgcn_s_setprio(1);
#define PRIO0    __builtin_amdgcn_s_setprio(0);

// A buffer stride 16384 u16; B buffer stride 8192 u16. i-tile stride 32*64=2048.
#define RD_A(DST, BO, KS) { _Pragma("unroll") for (int i_ = 0; i_ < 4; ++i_) \
    DST[i_] = *(const s16x8*)(pA + (BO) + i_ * 2048 + soff[KS]); }
#define RD_B(BM_, BP_, BO, KS) { \
    BM_ = *(const s16x8*)(pM + (BO) + soff[KS]); \
    BP_ = *(const s16x8*)(pP + (BO) + soff[KS]); }

#define MMA(AV, BMV, BPV) { _Pragma("unroll") for (int i_ = 0; i_ < 4; ++i_) { \
    accM[i_] = __builtin_amdgcn_mfma_f32_32x32x16_bf16(AV[i_], BMV, accM[i_], 0, 0, 0); \
    accP[i_] = __builtin_amdgcn_mfma_f32_32x32x16_bf16(AV[i_], BPV, accP[i_], 0, 0, 0); } }

// full K-step: stage t+1 into NXT buffer; 4 read/MFMA interleaved clusters
#define STEP(CUR, T) { \
    RD_A(a0, (CUR) * 16384, 0) RD_B(bm0, bp0, (CUR) * 8192, 0) \
    RD_A(a1, (CUR) * 16384, 1) RD_B(bm1, bp1, (CUR) * 8192, 1) \
    stA((CUR) ^ 1, (T) + 1, 0); stA((CUR) ^ 1, (T) + 1, 1); \
    stA((CUR) ^ 1, (T) + 1, 2); stA((CUR) ^ 1, (T) + 1, 3); \
    stM((CUR) ^ 1, (T) + 1, 0); stM((CUR) ^ 1, (T) + 1, 1); \
    stP((CUR) ^ 1, (T) + 1, 0); stP((CUR) ^ 1, (T) + 1, 1); \
    PRIO1 MMA(a0, bm0, bp0) PRIO0 \
    RD_A(a0, (CUR) * 16384, 2) RD_B(bm0, bp0, (CUR) * 8192, 2) \
    PRIO1 MMA(a1, bm1, bp1) PRIO0 \
    RD_A(a1, (CUR) * 16384, 3) RD_B(bm1, bp1, (CUR) * 8192, 3) \
    PRIO1 MMA(a0, bm0, bp0) PRIO0 \
    PRIO1 MMA(a1, bm1, bp1) PRIO0 \
    WAITV(0); BAR(); }

__global__ __launch_bounds__(512, 2) void gemm8_k(
    const u16* __restrict__ Bt, const u16* __restrict__ Wm, const u16* __restrict__ Wp,
    const float* __restrict__ bm, const float* __restrict__ bp,
    const float* __restrict__ asp,
    u16* __restrict__ item, float* __restrict__ scorep,
    int a0v_, int log2na, int nwg) {
    __shared__ u16 As[2][256 * 64];     // 64 KB (reused as epilogue tile)
    __shared__ u16 Bms[2][128 * 64];    // 32 KB
    __shared__ u16 Bps[2][128 * 64];    // 32 KB

    int bid = blockIdx.x;
    int chunk = nwg >> 3;                       // XCD-aware swizzle (nwg % 8 == 0)
    int b = (bid & 7) * chunk + (bid >> 3);
    int nt = b & 3;                             // N-tile fastest: share A panel
    int al = (b >> 2) & ((1 << log2na) - 1);
    int mt = b >> (2 + log2na);
    int a  = a0v_ + al;

    int tid = threadIdx.x;
    int lane = tid & 63;
    int w  = tid >> 6;        // 0..7
    int wr = w >> 2;          // 0..1  (M half)
    int wc = w & 3;           // 0..3  (N quarter)
    int h  = lane >> 5;       // lane half
    int r31 = lane & 31;

    const u16* Abase = Bt + (size_t)(mt * 256) * K2;
    const u16* Mbase = Wm + ((size_t)a * ND + nt * 128) * K2;
    const u16* Pbase = Wp + ((size_t)a * ND + nt * 128) * K2;

    // hoisted swizzled read bases: slot = (ks*2+h) ^ (r31&7), loop-invariant
    int soff[4];
    #pragma unroll
    for (int ks = 0; ks < 4; ++ks) soff[ks] = (((ks * 2 + h) ^ (r31 & 7)) << 3);
    const u16* pA = &As[0][(wr * 128 + r31) * 64];
    const u16* pM = &Bms[0][(wc * 32 + r31) * 64];
    const u16* pP = &Bps[0][(wc * 32 + r31) * 64];

    // staging: linear LDS dest, inverse-swizzled global source (unchanged geometry)
    int srow = tid >> 3, sq = tid & 7;
    int qsw = sq ^ (srow & 7);
    auto stA = [&](int buf, int ks, int r) {
        int row = r * 64 + srow;
        gload16(Abase + (size_t)row * K2 + ks * 64 + qsw * 8,
                (u16*)&As[buf][row * 64 + sq * 8]);
    };
    auto stM = [&](int buf, int ks, int r) {
        int row = r * 64 + srow;
        gload16(Mbase + (size_t)row * K2 + ks * 64 + qsw * 8,
                (u16*)&Bms[buf][row * 64 + sq * 8]);
    };
    auto stP = [&](int buf, int ks, int r) {
        int row = r * 64 + srow;
        gload16(Pbase + (size_t)row * K2 + ks * 64 + qsw * 8,
                (u16*)&Bps[buf][row * 64 + sq * 8]);
    };

    f32x16 accM[4], accP[4];
    #pragma unroll
    for (int i = 0; i < 4; ++i) { accM[i] = 0.0f; accP[i] = 0.0f; }

    s16x8 a0[4], a1[4], bm0, bp0, bm1, bp1;

    // ---- prologue: stage K0 into buf0 ----
    stA(0, 0, 0); stA(0, 0, 1); stA(0, 0, 2); stA(0, 0, 3);
    stM(0, 0, 0); stM(0, 0, 1);
    stP(0, 0, 0); stP(0, 0, 1);
    WAITV(0); BAR();

    // ---- steady loop: K-steps 0..14 ----
    for (int t = 0; t < 14; t += 2) {
        STEP(0, t)
        STEP(1, t + 1)
    }
    STEP(0, 14)     // stages ks=15 into buf1

    // ---- K-step 15: compute only (cur = 1) ----
    {
        RD_A(a0, 16384, 0) RD_B(bm0, bp0, 8192, 0)
        RD_A(a1, 16384, 1) RD_B(bm1, bp1, 8192, 1)
        PRIO1 MMA(a0, bm0, bp0) PRIO0
        RD_A(a0, 16384, 2) RD_B(bm0, bp0, 8192, 2)
        PRIO1 MMA(a1, bm1, bp1) PRIO0
        RD_A(a1, 16384, 3) RD_B(bm1, bp1, 8192, 3)
        PRIO1 MMA(a0, bm0, bp0) PRIO0
        PRIO1 MMA(a1, bm1, bp1) PRIO0
    }

    // ---- epilogue: gate into LDS tile, then coalesced store + fused scores ----
    // C/D layout 32x32: col = lane&31, row = (reg&3) + 8*(reg>>2) + 4*h
    BAR();   // all waves done with LDS reads; reuse As[0..1] as tile [256][128] u16
    u16* Tl = &As[0][0];
    {
        int col_l = wc * 32 + r31;              // 0..127
        int col_g = nt * 128 + col_l;
        float bmv = bm[a * ND + col_g];
        float bpv = bp[a * ND + col_g];
        #pragma unroll
        for (int i = 0; i < 4; ++i) {
            #pragma unroll
            for (int r = 0; r < 16; ++r) {
                float m = accM[i][r] + bmv;
                float p = accP[i][r] + bpv;
                float v = p / (1.0f + __expf(-m));
                int row_l = wr * 128 + i * 32 + (r & 3) + ((r >> 2) << 3) + 4 * h;
                Tl[row_l * 128 + col_l] = f2b(v);
            }
        }
    }
    BAR();
    // copy + score: 8 chunks/thread, chunk = (row, 8 cols); 16 threads per row
    {
        #pragma unroll
        for (int q = 0; q < 8; ++q) {
            int cid = q * 512 + tid;
            int row_l = cid >> 4;
            int c8 = (cid & 15) << 3;
            u16x8 tv = *(const u16x8*)&Tl[row_l * 128 + c8];
            int rowg = mt * 256 + row_l;
            int a2 = row_l & 7;
            int colg8 = nt * 128 + c8;
            f32x4 w0 = *(const f32x4*)&asp[a2 * ND + colg8];
            f32x4 w1 = *(const f32x4*)&asp[a2 * ND + colg8 + 4];
            float s = b2f(tv[0]) * w0[0] + b2f(tv[1]) * w0[1]
                    + b2f(tv[2]) * w0[2] + b2f(tv[3]) * w0[3]
                    + b2f(tv[4]) * w1[0] + b2f(tv[5]) * w1[1]
                    + b2f(tv[6]) * w1[2] + b2f(tv[7]) * w1[3];
            *(u16x8*)(item + ((size_t)al * MROWS + rowg) * ND + colg8) = tv;
            s += __shfl_xor(s, 1);
            s += __shfl_xor(s, 2);
            s += __shfl_xor(s, 4);
            s += __shfl_xor(s, 8);
            if ((tid & 15) == 0)
                scorep[((size_t)al * MROWS + rowg) * 4 + nt] = s;
        }
    }
}

// ---------------- kernel 4: softmax(L) from score partials + weighted sum ----------------
__global__ __launch_bounds__(512) void attn_out_k(
    const u16* __restrict__ item, const float* __restrict__ scorep,
    float* __restrict__ out, int b0) {
    __shared__ float attn[512];
    __shared__ float red[4][512];
    int t = threadIdx.x;
    int bl = blockIdx.x >> 3;
    int ap = blockIdx.x & 7;
    int bg = b0 + bl;

    size_t R = (size_t)bl * 4096 + (size_t)t * 8 + ap;
    f32x4 q = *(const f32x4*)(scorep + R * 4);
    float s = (q[0] + q[1]) + (q[2] + q[3]);

    red[0][t] = s;
    __syncthreads();
    for (int off = 256; off > 0; off >>= 1) {
        if (t < off) red[0][t] = fmaxf(red[0][t], red[0][t + off]);
        __syncthreads();
    }
    float mx = red[0][0];
    __syncthreads();
    float p = __expf(s - mx);
    red[0][t] = p;
    __syncthreads();
    for (int off = 256; off > 0; off >>= 1) {
        if (t < off) red[0][t] += red[0][t + off];
        __syncthreads();
    }
    float inv = 1.0f / red[0][0];
    attn[t] = p * inv;
    __syncthreads();

    // weighted sum: 4 l'-groups x 128 d-threads (4 d each), single item pass
    int gq = t >> 7, u = t & 127;
    float a0v = 0.f, a1v = 0.f, a2v = 0.f, a3v = 0.f;
    const u16* base2 = item + ((size_t)bl * 4096 + ap) * ND + 4 * u;
    for (int l = gq; l < 512; l += 4) {
        float wv = attn[l];
        u16x4 v = *(const u16x4*)(base2 + (size_t)l * 8 * ND);
        a0v += wv * b2f(v[0]); a1v += wv * b2f(v[1]);
        a2v += wv * b2f(v[2]); a3v += wv * b2f(v[3]);
    }
    red[gq][4 * u + 0] = a0v; red[gq][4 * u + 1] = a1v;
    red[gq][4 * u + 2] = a2v; red[gq][4 * u + 3] = a3v;
    __syncthreads();
    float o = red[0][t] + red[1][t] + red[2][t] + red[3][t];
    out[((size_t)bg * NA + ap) * ND + t] = o;
}

// ---------------- launcher ----------------
extern "C" void kernel_launch(void* const* d_in, const int* in_sizes, int n_in,
                              void* d_out, int out_size, void* d_ws, size_t ws_size,
                              hipStream_t stream) {
    const float* H   = (const float*)d_in[0];
    const float* U   = (const float*)d_in[1];
    const float* asp = (const float*)d_in[2];
    const float* Wmf = (const float*)d_in[3];
    const float* bmf = (const float*)d_in[4];
    const float* Wpf = (const float*)d_in[5];
    const float* bpf = (const float*)d_in[6];
    float* out = (float*)d_out;

    char* ws = (char*)d_ws;
    const size_t BATCH_BYTES = (size_t)MROWS * K2 * 2;        // 64 MB
    const size_t WT_BYTES    = (size_t)NA * ND * K2 * 2;      // 8 MB each
    u16* Bt = (u16*)(ws);
    u16* Wm = (u16*)(ws + BATCH_BYTES);
    u16* Wp = (u16*)(ws + BATCH_BYTES + WT_BYTES);
    size_t fixed = BATCH_BYTES + 2 * WT_BYTES;                 // 80 MB
    const size_t ITEM_PER_ASPECT  = (size_t)MROWS * ND * 2;    // 32 MB
    const size_t SCORE_PER_ASPECT = (size_t)MROWS * 4 * 4;     // 512 KB
    size_t avail = (ws_size > fixed) ? (ws_size - fixed) : 0;
    int na = (int)(avail / (ITEM_PER_ASPECT + SCORE_PER_ASPECT));
    if (na > NA) na = NA;
    if (na < 1) na = 1;
    int log2na = 0;
    while ((2 << log2na) <= na) ++log2na;
    na = 1 << log2na;
    u16*   item   = (u16*)(ws + fixed);
    float* scorep = (float*)(ws + fixed + (size_t)na * ITEM_PER_ASPECT);

    build_batch<<<4096, 256, 0, stream>>>(H, U, Bt);
    build_wt<<<4096, 256, 0, stream>>>(Wmf, Wpf, Wm, Wp);

    for (int a0 = 0; a0 < NA; a0 += na) {
        int n = (na < NA - a0) ? na : (NA - a0);
        gemm8_k<<<n * 512, 512, 0, stream>>>(Bt, Wm, Wp, bmf, bpf, asp,
                                             item, scorep, a0, log2na, n * 512);
        attn_out_k<<<n * 64, 512, 0, stream>>>(item, scorep, out, a0 * 8);
    }
}

// Round 9
// 585.206 us; speedup vs baseline: 1.2800x; 1.2800x over previous
//
#include <hip/hip_runtime.h>
#include <hip/hip_bf16.h>

// ---------------- types ----------------
typedef unsigned short u16;
typedef u16   u16x4 __attribute__((ext_vector_type(4)));
typedef u16   u16x8 __attribute__((ext_vector_type(8)));
typedef short s16x8 __attribute__((ext_vector_type(8)));
typedef float f32x4 __attribute__((ext_vector_type(4)));

// Problem constants
#define NB   64
#define NL   512
#define ND   512
#define NA   8
#define K2   1024        // 2*D (original concat K)
#define KH   512         // GEMM K after user-split (H part only)
#define MROWS 32768      // B*L

__device__ __forceinline__ float b2f(u16 u) {
    unsigned int x = ((unsigned int)u) << 16;
    return __uint_as_float(x);
}
__device__ __forceinline__ u16 f2b(float f) {
    unsigned int x = __float_as_uint(f);
    unsigned int r = (x + 0x7fffu + ((x >> 16) & 1u)) >> 16;
    return (u16)r;
}

// permuted column position for original k within a 64-col K-block (16x16x32 frag)
__device__ __forceinline__ int permc(int k) {
    int ks  = k >> 6;
    int kr  = k & 63;
    int kk  = kr >> 5;
    int k32 = kr & 31;
    int h   = k32 >> 4;
    int rem = k32 & 15;
    int g   = rem >> 2;
    int e0  = rem & 3;
    return ks * 64 + kk * 32 + g * 8 + h * 4 + e0;
}

__device__ __forceinline__ void gload16(const u16* g, u16* l) {
    __builtin_amdgcn_global_load_lds(
        (const __attribute__((address_space(1))) unsigned int*)g,
        (__attribute__((address_space(3))) unsigned int*)l, 16, 0, 0);
}

// ---------------- kernel 1: build permuted bf16 H-matrix [32768][512] ----------------
__global__ void build_batch(const float* __restrict__ H, u16* __restrict__ Bt) {
    size_t stride = (size_t)gridDim.x * blockDim.x;
    for (size_t idx = (size_t)blockIdx.x * blockDim.x + threadIdx.x;
         idx < (size_t)MROWS * 128; idx += stride) {
        int r  = (int)(idx >> 7);
        int c  = ((int)idx & 127) << 2;       // permuted col (multiple of 4)
        int ks = c >> 6;
        int w64 = c & 63;
        int cq = w64 >> 3;
        int h  = (w64 >> 2) & 1;
        int kbase = ks * 64 + (cq >> 2) * 32 + (cq & 3) * 4 + h * 16;  // < 512
        f32x4 v = *(const f32x4*)(H + (size_t)r * ND + kbase);
        u16x4 o;
        o[0] = f2b(v[0]); o[1] = f2b(v[1]); o[2] = f2b(v[2]); o[3] = f2b(v[3]);
        *(u16x4*)(Bt + (size_t)r * KH + c) = o;
    }
}

// ---------------- kernel 2: W top half (k<512) -> Wt (A,512,512) bf16 permuted ----------------
__global__ void build_wt(const float* __restrict__ Wmf, const float* __restrict__ Wpf,
                         u16* __restrict__ Wm, u16* __restrict__ Wp) {
    __shared__ float ld[32][65];
    int bid = blockIdx.x;
    int kt  = bid & 15;            // 16 x 32 = 512 k
    int dt  = (bid >> 4) & 7;
    int a   = (bid >> 7) & 7;
    int mat = bid >> 10;
    const float* W = mat ? Wpf : Wmf;
    u16* Wt = mat ? Wp : Wm;
    int k0 = kt * 32, d0 = dt * 64;
    int t = threadIdx.x;
    #pragma unroll
    for (int it = 0; it < 8; ++it) {
        int lin = it * 256 + t;
        int i = lin >> 6, j = lin & 63;
        ld[i][j] = W[((size_t)a * K2 + k0 + i) * ND + d0 + j];
    }
    __syncthreads();
    #pragma unroll
    for (int it = 0; it < 8; ++it) {
        int lin = it * 256 + t;
        int dl = lin >> 5, kl = lin & 31;
        int k = k0 + kl;
        Wt[((size_t)a * ND + d0 + dl) * KH + permc(k)] = f2b(ld[kl][dl]);
    }
}

// ---------------- kernel 2b: user term  uX[a][b][col] = sum_k U[b][k] * W[a][512+k][col] ----------------
// grid = 128: a(8) x mat(2) x colgroup(8); 256 threads = 64 cols x 4 b-quarters
__global__ __launch_bounds__(256) void user_mm(
    const float* __restrict__ U, const float* __restrict__ Wmf,
    const float* __restrict__ Wpf, float* __restrict__ uM, float* __restrict__ uP) {
    __shared__ float wl[64][64];
    __shared__ float ul[64][64];
    int bid = blockIdx.x;
    int a   = bid & 7;
    int mat = (bid >> 3) & 1;
    int cg  = bid >> 4;
    int col0 = cg * 64;
    const float* W = mat ? Wpf : Wmf;
    float* uX = mat ? uP : uM;
    int t = threadIdx.x;
    int c = t & 63, bq = t >> 6;           // col_local, b-quarter

    float acc[16];
    #pragma unroll
    for (int i = 0; i < 16; ++i) acc[i] = 0.0f;

    for (int kt = 0; kt < 8; ++kt) {
        int k0 = kt * 64;
        #pragma unroll
        for (int i = 0; i < 16; ++i)
            wl[bq * 16 + i][c] = W[((size_t)a * K2 + 512 + k0 + bq * 16 + i) * ND + col0 + c];
        #pragma unroll
        for (int i = 0; i < 16; ++i) {
            int idx = i * 256 + t;
            ul[idx >> 6][idx & 63] = U[(size_t)(idx >> 6) * ND + k0 + (idx & 63)];
        }
        __syncthreads();
        #pragma unroll
        for (int b2 = 0; b2 < 16; ++b2) {
            float s = 0.0f;
            #pragma unroll
            for (int k = 0; k < 64; ++k)
                s += ul[bq * 16 + b2][k] * wl[k][c];
            acc[b2] += s;
        }
        __syncthreads();
    }
    #pragma unroll
    for (int b2 = 0; b2 < 16; ++b2)
        uX[((size_t)a * NB + bq * 16 + b2) * ND + col0 + c] = acc[b2];
}

// ---------------- kernel 3: K=512 dual GEMM + user-fold + gate + fused scores ----------------
// BM=256, BN=128, BK=64, 8 waves (2M x 4N), double-buffered LDS, stage 1 ahead.
// One barrier + one vmcnt per K-step; read-batches interleaved with MFMA clusters.
#define BAR()    do { __builtin_amdgcn_sched_barrier(0); \
                      __builtin_amdgcn_s_barrier(); \
                      __builtin_amdgcn_sched_barrier(0); } while (0)
#define WAITV(n) do { asm volatile("s_waitcnt vmcnt(" #n ")" ::: "memory"); \
                      __builtin_amdgcn_sched_barrier(0); } while (0)
#define PRIO1    __builtin_amdgcn_s_setprio(1);
#define PRIO0    __builtin_amdgcn_s_setprio(0);

// A buffer stride: 256*64 = 16384 u16; B buffer stride: 128*64 = 8192 u16.
#define RDAE(BO) { _Pragma("unroll") for (int f_ = 0; f_ < 4; ++f_) { \
    af0[f_ * 2 + 0] = *(const s16x8*)(pA0 + (BO) + f_ * 1024); \
    af0[f_ * 2 + 1] = *(const s16x8*)(pA1 + (BO) + f_ * 1024); } }
#define RDAO(BO) { _Pragma("unroll") for (int f_ = 0; f_ < 4; ++f_) { \
    af1[f_ * 2 + 0] = *(const s16x8*)(pA0 + (BO) + 4096 + f_ * 1024); \
    af1[f_ * 2 + 1] = *(const s16x8*)(pA1 + (BO) + 4096 + f_ * 1024); } }
#define RDFM(BO) { _Pragma("unroll") for (int j_ = 0; j_ < 2; ++j_) { \
    fm[j_ * 2 + 0] = *(const s16x8*)(pM0 + (BO) + j_ * 1024); \
    fm[j_ * 2 + 1] = *(const s16x8*)(pM1 + (BO) + j_ * 1024); } }
#define RDFP(BO) { _Pragma("unroll") for (int j_ = 0; j_ < 2; ++j_) { \
    fp[j_ * 2 + 0] = *(const s16x8*)(pP0 + (BO) + j_ * 1024); \
    fp[j_ * 2 + 1] = *(const s16x8*)(pP1 + (BO) + j_ * 1024); } }

#define MMA_M(AF,F0) \
    _Pragma("unroll") for (int kk_ = 0; kk_ < 2; ++kk_) \
    _Pragma("unroll") for (int f_ = 0; f_ < 4; ++f_) \
    _Pragma("unroll") for (int j_ = 0; j_ < 2; ++j_) \
        accM[(F0) + f_][j_] = __builtin_amdgcn_mfma_f32_16x16x32_bf16( \
            AF[f_ * 2 + kk_], fm[j_ * 2 + kk_], accM[(F0) + f_][j_], 0, 0, 0);

#define MMA_P(AF,F0) \
    _Pragma("unroll") for (int kk_ = 0; kk_ < 2; ++kk_) \
    _Pragma("unroll") for (int f_ = 0; f_ < 4; ++f_) \
    _Pragma("unroll") for (int j_ = 0; j_ < 2; ++j_) \
        accP[(F0) + f_][j_] = __builtin_amdgcn_mfma_f32_16x16x32_bf16( \
            AF[f_ * 2 + kk_], fp[j_ * 2 + kk_], accP[(F0) + f_][j_], 0, 0, 0);

// full K-step: stages for T+1 into NXT buffer, read-batches interleaved with MFMA
#define STEP(CUR, T) { \
    stA((CUR) ^ 1, (T) + 1, 0); stA((CUR) ^ 1, (T) + 1, 1); \
    stA((CUR) ^ 1, (T) + 1, 2); stA((CUR) ^ 1, (T) + 1, 3); \
    stM((CUR) ^ 1, (T) + 1, 0); stM((CUR) ^ 1, (T) + 1, 1); \
    stP((CUR) ^ 1, (T) + 1, 0); stP((CUR) ^ 1, (T) + 1, 1); \
    RDAE((CUR) * 16384) RDFM((CUR) * 8192) \
    PRIO1 MMA_M(af0, 0) PRIO0 \
    RDFP((CUR) * 8192) \
    PRIO1 MMA_P(af0, 0) PRIO0 \
    RDAO((CUR) * 16384) \
    PRIO1 MMA_M(af1, 4) PRIO0 \
    PRIO1 MMA_P(af1, 4) PRIO0 \
    WAITV(0); BAR(); }

__global__ __launch_bounds__(512, 2) void gemm8_k(
    const u16* __restrict__ Bt, const u16* __restrict__ Wm, const u16* __restrict__ Wp,
    const float* __restrict__ bm, const float* __restrict__ bp,
    const float* __restrict__ uM, const float* __restrict__ uP,
    const float* __restrict__ asp,
    u16* __restrict__ item, float* __restrict__ scorep,
    int a0, int log2na, int nwg) {
    __shared__ u16 As[2][256 * 64];     // 64 KB
    __shared__ u16 Bms[2][128 * 64];    // 32 KB
    __shared__ u16 Bps[2][128 * 64];    // 32 KB

    int bid = blockIdx.x;
    int chunk = nwg >> 3;                       // XCD-aware swizzle (nwg % 8 == 0)
    int b = (bid & 7) * chunk + (bid >> 3);
    int nt = b & 3;                             // N-tile fastest: share A panel
    int al = (b >> 2) & ((1 << log2na) - 1);
    int mt = b >> (2 + log2na);
    int a  = a0 + al;

    int tid = threadIdx.x;
    int lane = tid & 63;
    int w  = tid >> 6;        // 0..7
    int wr = w >> 2;          // 0..1  (M half)
    int wc = w & 3;           // 0..3  (N quarter)
    int g = lane >> 4, r15 = lane & 15;

    const u16* Abase = Bt + (size_t)(mt * 256) * KH;
    const u16* Mbase = Wm + ((size_t)a * ND + nt * 128) * KH;
    const u16* Pbase = Wp + ((size_t)a * ND + nt * 128) * KH;

    // ---- hoisted swizzled read bases: slot XOR is loop-invariant ----
    int s0 = g ^ (r15 & 7);            // kk=0 slot
    int s1 = (4 + g) ^ (r15 & 7);      // kk=1 slot
    const u16* pA0 = &As[0][(wr * 128 + r15) * 64 + s0 * 8];
    const u16* pA1 = &As[0][(wr * 128 + r15) * 64 + s1 * 8];
    const u16* pM0 = &Bms[0][(wc * 32 + r15) * 64 + s0 * 8];
    const u16* pM1 = &Bms[0][(wc * 32 + r15) * 64 + s1 * 8];
    const u16* pP0 = &Bps[0][(wc * 32 + r15) * 64 + s0 * 8];
    const u16* pP1 = &Bps[0][(wc * 32 + r15) * 64 + s1 * 8];

    // ---- staging: linear LDS dest, inverse-swizzled global source ----
    int srow = tid >> 3, sq = tid & 7;
    int qsw = sq ^ (srow & 7);
    auto stA = [&](int buf, int ks, int r) {
        int row = r * 64 + srow;
        gload16(Abase + (size_t)row * KH + ks * 64 + qsw * 8,
                (u16*)&As[buf][row * 64 + sq * 8]);
    };
    auto stM = [&](int buf, int ks, int r) {
        int row = r * 64 + srow;
        gload16(Mbase + (size_t)row * KH + ks * 64 + qsw * 8,
                (u16*)&Bms[buf][row * 64 + sq * 8]);
    };
    auto stP = [&](int buf, int ks, int r) {
        int row = r * 64 + srow;
        gload16(Pbase + (size_t)row * KH + ks * 64 + qsw * 8,
                (u16*)&Bps[buf][row * 64 + sq * 8]);
    };

    f32x4 accM[8][2], accP[8][2];
    #pragma unroll
    for (int i = 0; i < 8; ++i)
        #pragma unroll
        for (int j = 0; j < 2; ++j) { accM[i][j] = 0.0f; accP[i][j] = 0.0f; }

    s16x8 af0[8], af1[8], fm[4], fp[4];

    // ---- prologue: stage K0 into buf0 ----
    stA(0, 0, 0); stA(0, 0, 1); stA(0, 0, 2); stA(0, 0, 3);
    stM(0, 0, 0); stM(0, 0, 1);
    stP(0, 0, 0); stP(0, 0, 1);
    WAITV(0); BAR();

    // ---- steady loop: K-steps 0..6 (8 total, K=512) ----
    for (int t = 0; t < 6; t += 2) {
        STEP(0, t)
        STEP(1, t + 1)
    }
    STEP(0, 6)      // stages ks=7 into buf1

    // ---- K-step 7: compute only (cur = 1) ----
    {
        RDAE(16384) RDFM(8192)
        PRIO1 MMA_M(af0, 0) PRIO0
        RDFP(8192)
        PRIO1 MMA_P(af0, 0) PRIO0
        RDAO(16384)
        PRIO1 MMA_M(af1, 4) PRIO0
        PRIO1 MMA_P(af1, 4) PRIO0
    }

    // ---- epilogue: bias + user-term fold + sigmoid gate, item write, scores ----
    int gc0 = nt * 128 + wc * 32 + r15;
    int gc1 = gc0 + 16;
    int bix = mt >> 1;                  // batch index: rows [mt*256, mt*256+256) -> b = mt/2
    size_t ub = ((size_t)a * NB + bix) * ND;
    float bmv0 = bm[a * ND + gc0] + uM[ub + gc0];
    float bmv1 = bm[a * ND + gc1] + uM[ub + gc1];
    float bpv0 = bp[a * ND + gc0] + uP[ub + gc0];
    float bpv1 = bp[a * ND + gc1] + uP[ub + gc1];
    float aspw[4][2];
    #pragma unroll
    for (int jj = 0; jj < 4; ++jj) {
        int a2 = (g * 4 + jj) & 7;
        aspw[jj][0] = asp[a2 * ND + gc0];
        aspw[jj][1] = asp[a2 * ND + gc1];
    }
    #pragma unroll
    for (int i = 0; i < 8; ++i) {
        int rowb = mt * 256 + wr * 128 + i * 16 + g * 4;
        #pragma unroll
        for (int jj = 0; jj < 4; ++jj) {
            float m0 = accM[i][0][jj] + bmv0;
            float p0 = accP[i][0][jj] + bpv0;
            float v0 = p0 / (1.0f + __expf(-m0));
            float m1 = accM[i][1][jj] + bmv1;
            float p1 = accP[i][1][jj] + bpv1;
            float v1 = p1 / (1.0f + __expf(-m1));
            size_t rbase = ((size_t)al * MROWS + rowb + jj) * ND;
            item[rbase + gc0] = f2b(v0);
            item[rbase + gc1] = f2b(v1);
            float sv = v0 * aspw[jj][0] + v1 * aspw[jj][1];
            sv += __shfl_xor(sv, 1);
            sv += __shfl_xor(sv, 2);
            sv += __shfl_xor(sv, 4);
            sv += __shfl_xor(sv, 8);
            if (r15 == 0)
                scorep[((size_t)al * MROWS + rowb + jj) * 16 + nt * 4 + wc] = sv;
        }
    }
}

// ---------------- kernel 4: softmax(L) from score partials + weighted sum ----------------
__global__ __launch_bounds__(512) void attn_out_k(
    const u16* __restrict__ item, const float* __restrict__ scorep,
    float* __restrict__ out, int b0) {
    __shared__ float attn[512];
    __shared__ float red[4][512];
    int t = threadIdx.x;
    int bl = blockIdx.x >> 3;
    int ap = blockIdx.x & 7;
    int bg = b0 + bl;

    size_t R = (size_t)bl * 4096 + (size_t)t * 8 + ap;
    const f32x4* sp = (const f32x4*)(scorep + R * 16);
    f32x4 q0 = sp[0], q1 = sp[1], q2 = sp[2], q3 = sp[3];
    float s = (q0[0] + q0[1] + q0[2] + q0[3]) + (q1[0] + q1[1] + q1[2] + q1[3])
            + (q2[0] + q2[1] + q2[2] + q2[3]) + (q3[0] + q3[1] + q3[2] + q3[3]);

    red[0][t] = s;
    __syncthreads();
    for (int off = 256; off > 0; off >>= 1) {
        if (t < off) red[0][t] = fmaxf(red[0][t], red[0][t + off]);
        __syncthreads();
    }
    float mx = red[0][0];
    __syncthreads();
    float p = __expf(s - mx);
    red[0][t] = p;
    __syncthreads();
    for (int off = 256; off > 0; off >>= 1) {
        if (t < off) red[0][t] += red[0][t + off];
        __syncthreads();
    }
    float inv = 1.0f / red[0][0];
    attn[t] = p * inv;
    __syncthreads();

    // weighted sum: 4 l'-groups x 128 d-threads (4 d each), single item pass
    int gq = t >> 7, u = t & 127;
    float a0v = 0.f, a1v = 0.f, a2v = 0.f, a3v = 0.f;
    const u16* base2 = item + ((size_t)bl * 4096 + ap) * ND + 4 * u;
    for (int l = gq; l < 512; l += 4) {
        float wv = attn[l];
        u16x4 v = *(const u16x4*)(base2 + (size_t)l * 8 * ND);
        a0v += wv * b2f(v[0]); a1v += wv * b2f(v[1]);
        a2v += wv * b2f(v[2]); a3v += wv * b2f(v[3]);
    }
    red[gq][4 * u + 0] = a0v; red[gq][4 * u + 1] = a1v;
    red[gq][4 * u + 2] = a2v; red[gq][4 * u + 3] = a3v;
    __syncthreads();
    float o = red[0][t] + red[1][t] + red[2][t] + red[3][t];
    out[((size_t)bg * NA + ap) * ND + t] = o;
}

// ---------------- launcher ----------------
extern "C" void kernel_launch(void* const* d_in, const int* in_sizes, int n_in,
                              void* d_out, int out_size, void* d_ws, size_t ws_size,
                              hipStream_t stream) {
    const float* H   = (const float*)d_in[0];
    const float* U   = (const float*)d_in[1];
    const float* asp = (const float*)d_in[2];
    const float* Wmf = (const float*)d_in[3];
    const float* bmf = (const float*)d_in[4];
    const float* Wpf = (const float*)d_in[5];
    const float* bpf = (const float*)d_in[6];
    float* out = (float*)d_out;

    char* ws = (char*)d_ws;
    const size_t BT_BYTES = (size_t)MROWS * KH * 2;            // 32 MB
    const size_t WT_BYTES = (size_t)NA * ND * KH * 2;          // 4 MB each
    const size_t U_BYTES  = (size_t)NA * NB * ND * 4;          // 1 MB each
    u16*   Bt = (u16*)(ws);
    u16*   Wm = (u16*)(ws + BT_BYTES);
    u16*   Wp = (u16*)(ws + BT_BYTES + WT_BYTES);
    float* uM = (float*)(ws + BT_BYTES + 2 * WT_BYTES);
    float* uP = (float*)(ws + BT_BYTES + 2 * WT_BYTES + U_BYTES);
    size_t fixed = BT_BYTES + 2 * WT_BYTES + 2 * U_BYTES;      // 42 MB
    const size_t ITEM_PER_ASPECT  = (size_t)MROWS * ND * 2;    // 32 MB
    const size_t SCORE_PER_ASPECT = (size_t)MROWS * 16 * 4;    // 2 MB
    size_t avail = (ws_size > fixed) ? (ws_size - fixed) : 0;
    int na = (int)(avail / (ITEM_PER_ASPECT + SCORE_PER_ASPECT));
    if (na > NA) na = NA;
    if (na < 1) na = 1;
    int log2na = 0;
    while ((2 << log2na) <= na) ++log2na;
    na = 1 << log2na;
    u16*   item   = (u16*)(ws + fixed);
    float* scorep = (float*)(ws + fixed + (size_t)na * ITEM_PER_ASPECT);

    build_batch<<<4096, 256, 0, stream>>>(H, Bt);
    build_wt<<<2048, 256, 0, stream>>>(Wmf, Wpf, Wm, Wp);
    user_mm<<<128, 256, 0, stream>>>(U, Wmf, Wpf, uM, uP);

    for (int a0 = 0; a0 < NA; a0 += na) {
        int n = (na < NA - a0) ? na : (NA - a0);
        gemm8_k<<<n * 512, 512, 0, stream>>>(Bt, Wm, Wp, bmf, bpf, uM, uP, asp,
                                             item, scorep, a0, log2na, n * 512);
        attn_out_k<<<n * 64, 512, 0, stream>>>(item, scorep, out, a0 * 8);
    }
}

// Round 10
// 569.753 us; speedup vs baseline: 1.3147x; 1.0271x over previous
//
#include <hip/hip_runtime.h>
#include <hip/hip_bf16.h>

// ---------------- types ----------------
typedef unsigned short u16;
typedef u16   u16x4 __attribute__((ext_vector_type(4)));
typedef u16   u16x8 __attribute__((ext_vector_type(8)));
typedef short s16x8 __attribute__((ext_vector_type(8)));
typedef float f32x4 __attribute__((ext_vector_type(4)));

// Problem constants
#define NB   64
#define NL   512
#define ND   512
#define NA   8
#define K2   1024        // 2*D (original concat K)
#define KH   512         // GEMM K after user-split (H part only)
#define MROWS 32768      // B*L

__device__ __forceinline__ float b2f(u16 u) {
    unsigned int x = ((unsigned int)u) << 16;
    return __uint_as_float(x);
}
__device__ __forceinline__ u16 f2b(float f) {
    unsigned int x = __float_as_uint(f);
    unsigned int r = (x + 0x7fffu + ((x >> 16) & 1u)) >> 16;
    return (u16)r;
}

// permuted column position for original k within a 64-col K-block (16x16x32 frag)
__device__ __forceinline__ int permc(int k) {
    int ks  = k >> 6;
    int kr  = k & 63;
    int kk  = kr >> 5;
    int k32 = kr & 31;
    int h   = k32 >> 4;
    int rem = k32 & 15;
    int g   = rem >> 2;
    int e0  = rem & 3;
    return ks * 64 + kk * 32 + g * 8 + h * 4 + e0;
}

__device__ __forceinline__ void gload16(const u16* g, u16* l) {
    __builtin_amdgcn_global_load_lds(
        (const __attribute__((address_space(1))) unsigned int*)g,
        (__attribute__((address_space(3))) unsigned int*)l, 16, 0, 0);
}

// ---------------- kernel 1: build permuted bf16 H-matrix [32768][512] ----------------
__global__ void build_batch(const float* __restrict__ H, u16* __restrict__ Bt) {
    size_t stride = (size_t)gridDim.x * blockDim.x;
    for (size_t idx = (size_t)blockIdx.x * blockDim.x + threadIdx.x;
         idx < (size_t)MROWS * 128; idx += stride) {
        int r  = (int)(idx >> 7);
        int c  = ((int)idx & 127) << 2;       // permuted col (multiple of 4)
        int ks = c >> 6;
        int w64 = c & 63;
        int cq = w64 >> 3;
        int h  = (w64 >> 2) & 1;
        int kbase = ks * 64 + (cq >> 2) * 32 + (cq & 3) * 4 + h * 16;  // < 512
        f32x4 v = *(const f32x4*)(H + (size_t)r * ND + kbase);
        u16x4 o;
        o[0] = f2b(v[0]); o[1] = f2b(v[1]); o[2] = f2b(v[2]); o[3] = f2b(v[3]);
        *(u16x4*)(Bt + (size_t)r * KH + c) = o;
    }
}

// ---------------- kernel 2: W top half (k<512) -> Wt (A,512,512) bf16 permuted ----------------
__global__ void build_wt(const float* __restrict__ Wmf, const float* __restrict__ Wpf,
                         u16* __restrict__ Wm, u16* __restrict__ Wp) {
    __shared__ float ld[32][65];
    int bid = blockIdx.x;
    int kt  = bid & 15;            // 16 x 32 = 512 k
    int dt  = (bid >> 4) & 7;
    int a   = (bid >> 7) & 7;
    int mat = bid >> 10;
    const float* W = mat ? Wpf : Wmf;
    u16* Wt = mat ? Wp : Wm;
    int k0 = kt * 32, d0 = dt * 64;
    int t = threadIdx.x;
    #pragma unroll
    for (int it = 0; it < 8; ++it) {
        int lin = it * 256 + t;
        int i = lin >> 6, j = lin & 63;
        ld[i][j] = W[((size_t)a * K2 + k0 + i) * ND + d0 + j];
    }
    __syncthreads();
    #pragma unroll
    for (int it = 0; it < 8; ++it) {
        int lin = it * 256 + t;
        int dl = lin >> 5, kl = lin & 31;
        int k = k0 + kl;
        Wt[((size_t)a * ND + d0 + dl) * KH + permc(k)] = f2b(ld[kl][dl]);
    }
}

// ---------------- kernel 2b: user term  uX[a][b][col] = sum_k U[b][k] * W[a][512+k][col] ----------------
__global__ __launch_bounds__(256) void user_mm(
    const float* __restrict__ U, const float* __restrict__ Wmf,
    const float* __restrict__ Wpf, float* __restrict__ uM, float* __restrict__ uP) {
    __shared__ float wl[64][64];
    __shared__ float ul[64][64];
    int bid = blockIdx.x;
    int a   = bid & 7;
    int mat = (bid >> 3) & 1;
    int cg  = bid >> 4;
    int col0 = cg * 64;
    const float* W = mat ? Wpf : Wmf;
    float* uX = mat ? uP : uM;
    int t = threadIdx.x;
    int c = t & 63, bq = t >> 6;           // col_local, b-quarter

    float acc[16];
    #pragma unroll
    for (int i = 0; i < 16; ++i) acc[i] = 0.0f;

    for (int kt = 0; kt < 8; ++kt) {
        int k0 = kt * 64;
        #pragma unroll
        for (int i = 0; i < 16; ++i)
            wl[bq * 16 + i][c] = W[((size_t)a * K2 + 512 + k0 + bq * 16 + i) * ND + col0 + c];
        #pragma unroll
        for (int i = 0; i < 16; ++i) {
            int idx = i * 256 + t;
            ul[idx >> 6][idx & 63] = U[(size_t)(idx >> 6) * ND + k0 + (idx & 63)];
        }
        __syncthreads();
        #pragma unroll
        for (int b2 = 0; b2 < 16; ++b2) {
            float s = 0.0f;
            #pragma unroll
            for (int k = 0; k < 64; ++k)
                s += ul[bq * 16 + b2][k] * wl[k][c];
            acc[b2] += s;
        }
        __syncthreads();
    }
    #pragma unroll
    for (int b2 = 0; b2 < 16; ++b2)
        uX[((size_t)a * NB + bq * 16 + b2) * ND + col0 + c] = acc[b2];
}

// ---------------- kernel 3: K=512 dual GEMM + user-fold + gate + LDS-tiled epilogue ----------------
// BM=256, BN=128, BK=64, 8 waves (2M x 4N), double-buffered LDS, stage 1 ahead.
#define BAR()    do { __builtin_amdgcn_sched_barrier(0); \
                      __builtin_amdgcn_s_barrier(); \
                      __builtin_amdgcn_sched_barrier(0); } while (0)
#define WAITV(n) do { asm volatile("s_waitcnt vmcnt(" #n ")" ::: "memory"); \
                      __builtin_amdgcn_sched_barrier(0); } while (0)
#define PRIO1    __builtin_amdgcn_s_setprio(1);
#define PRIO0    __builtin_amdgcn_s_setprio(0);

// LDS pool (u16 units): A bufs at 0 (2x16384), Bm at 32768 (2x8192), Bp at 49152.
#define A_OFF  0
#define M_OFF  32768
#define P_OFF  49152
#define TSTRIDE 136   // epilogue tile row stride (u16)

#define RDAE(BO) { _Pragma("unroll") for (int f_ = 0; f_ < 4; ++f_) { \
    af0[f_ * 2 + 0] = *(const s16x8*)(pA0 + (BO) + f_ * 1024); \
    af0[f_ * 2 + 1] = *(const s16x8*)(pA1 + (BO) + f_ * 1024); } }
#define RDAO(BO) { _Pragma("unroll") for (int f_ = 0; f_ < 4; ++f_) { \
    af1[f_ * 2 + 0] = *(const s16x8*)(pA0 + (BO) + 4096 + f_ * 1024); \
    af1[f_ * 2 + 1] = *(const s16x8*)(pA1 + (BO) + 4096 + f_ * 1024); } }
#define RDFM(BO) { _Pragma("unroll") for (int j_ = 0; j_ < 2; ++j_) { \
    fm[j_ * 2 + 0] = *(const s16x8*)(pM0 + (BO) + j_ * 1024); \
    fm[j_ * 2 + 1] = *(const s16x8*)(pM1 + (BO) + j_ * 1024); } }
#define RDFP(BO) { _Pragma("unroll") for (int j_ = 0; j_ < 2; ++j_) { \
    fp[j_ * 2 + 0] = *(const s16x8*)(pP0 + (BO) + j_ * 1024); \
    fp[j_ * 2 + 1] = *(const s16x8*)(pP1 + (BO) + j_ * 1024); } }

#define MMA_M(AF,F0) \
    _Pragma("unroll") for (int kk_ = 0; kk_ < 2; ++kk_) \
    _Pragma("unroll") for (int f_ = 0; f_ < 4; ++f_) \
    _Pragma("unroll") for (int j_ = 0; j_ < 2; ++j_) \
        accM[(F0) + f_][j_] = __builtin_amdgcn_mfma_f32_16x16x32_bf16( \
            AF[f_ * 2 + kk_], fm[j_ * 2 + kk_], accM[(F0) + f_][j_], 0, 0, 0);

#define MMA_P(AF,F0) \
    _Pragma("unroll") for (int kk_ = 0; kk_ < 2; ++kk_) \
    _Pragma("unroll") for (int f_ = 0; f_ < 4; ++f_) \
    _Pragma("unroll") for (int j_ = 0; j_ < 2; ++j_) \
        accP[(F0) + f_][j_] = __builtin_amdgcn_mfma_f32_16x16x32_bf16( \
            AF[f_ * 2 + kk_], fp[j_ * 2 + kk_], accP[(F0) + f_][j_], 0, 0, 0);

#define STEP(CUR, T) { \
    stA((CUR) ^ 1, (T) + 1, 0); stA((CUR) ^ 1, (T) + 1, 1); \
    stA((CUR) ^ 1, (T) + 1, 2); stA((CUR) ^ 1, (T) + 1, 3); \
    stM((CUR) ^ 1, (T) + 1, 0); stM((CUR) ^ 1, (T) + 1, 1); \
    stP((CUR) ^ 1, (T) + 1, 0); stP((CUR) ^ 1, (T) + 1, 1); \
    RDAE((CUR) * 16384) RDFM((CUR) * 8192) \
    PRIO1 MMA_M(af0, 0) PRIO0 \
    RDFP((CUR) * 8192) \
    PRIO1 MMA_P(af0, 0) PRIO0 \
    RDAO((CUR) * 16384) \
    PRIO1 MMA_M(af1, 4) PRIO0 \
    PRIO1 MMA_P(af1, 4) PRIO0 \
    WAITV(0); BAR(); }

__global__ __launch_bounds__(512, 2) void gemm8_k(
    const u16* __restrict__ Bt, const u16* __restrict__ Wm, const u16* __restrict__ Wp,
    const float* __restrict__ bm, const float* __restrict__ bp,
    const float* __restrict__ uM, const float* __restrict__ uP,
    const float* __restrict__ asp,
    u16* __restrict__ item, float* __restrict__ scorep,
    int a0, int log2na, int nwg) {
    __shared__ u16 smem[65536];         // 128 KB pool

    int bid = blockIdx.x;
    int chunk = nwg >> 3;                       // XCD-aware swizzle (nwg % 8 == 0)
    int b = (bid & 7) * chunk + (bid >> 3);
    int nt = b & 3;                             // N-tile fastest: share A panel
    int al = (b >> 2) & ((1 << log2na) - 1);
    int mt = b >> (2 + log2na);
    int a  = a0 + al;

    int tid = threadIdx.x;
    int lane = tid & 63;
    int w  = tid >> 6;        // 0..7
    int wr = w >> 2;          // 0..1  (M half)
    int wc = w & 3;           // 0..3  (N quarter)
    int g = lane >> 4, r15 = lane & 15;

    const u16* Abase = Bt + (size_t)(mt * 256) * KH;
    const u16* Mbase = Wm + ((size_t)a * ND + nt * 128) * KH;
    const u16* Pbase = Wp + ((size_t)a * ND + nt * 128) * KH;

    // ---- hoisted swizzled read bases ----
    int s0 = g ^ (r15 & 7);
    int s1 = (4 + g) ^ (r15 & 7);
    const u16* pA0 = &smem[A_OFF + (wr * 128 + r15) * 64 + s0 * 8];
    const u16* pA1 = &smem[A_OFF + (wr * 128 + r15) * 64 + s1 * 8];
    const u16* pM0 = &smem[M_OFF + (wc * 32 + r15) * 64 + s0 * 8];
    const u16* pM1 = &smem[M_OFF + (wc * 32 + r15) * 64 + s1 * 8];
    const u16* pP0 = &smem[P_OFF + (wc * 32 + r15) * 64 + s0 * 8];
    const u16* pP1 = &smem[P_OFF + (wc * 32 + r15) * 64 + s1 * 8];

    // ---- staging: linear LDS dest, inverse-swizzled global source ----
    int srow = tid >> 3, sq = tid & 7;
    int qsw = sq ^ (srow & 7);
    auto stA = [&](int buf, int ks, int r) {
        int row = r * 64 + srow;
        gload16(Abase + (size_t)row * KH + ks * 64 + qsw * 8,
                &smem[A_OFF + buf * 16384 + row * 64 + sq * 8]);
    };
    auto stM = [&](int buf, int ks, int r) {
        int row = r * 64 + srow;
        gload16(Mbase + (size_t)row * KH + ks * 64 + qsw * 8,
                &smem[M_OFF + buf * 8192 + row * 64 + sq * 8]);
    };
    auto stP = [&](int buf, int ks, int r) {
        int row = r * 64 + srow;
        gload16(Pbase + (size_t)row * KH + ks * 64 + qsw * 8,
                &smem[P_OFF + buf * 8192 + row * 64 + sq * 8]);
    };

    f32x4 accM[8][2], accP[8][2];
    #pragma unroll
    for (int i = 0; i < 8; ++i)
        #pragma unroll
        for (int j = 0; j < 2; ++j) { accM[i][j] = 0.0f; accP[i][j] = 0.0f; }

    s16x8 af0[8], af1[8], fm[4], fp[4];

    // ---- prologue: stage K0 into buf0 ----
    stA(0, 0, 0); stA(0, 0, 1); stA(0, 0, 2); stA(0, 0, 3);
    stM(0, 0, 0); stM(0, 0, 1);
    stP(0, 0, 0); stP(0, 0, 1);
    WAITV(0); BAR();

    // ---- steady loop: K-steps 0..6 (8 total, K=512) ----
    for (int t = 0; t < 6; t += 2) {
        STEP(0, t)
        STEP(1, t + 1)
    }
    STEP(0, 6)      // stages ks=7 into buf1

    // ---- K-step 7: compute only (cur = 1) ----
    {
        RDAE(16384) RDFM(8192)
        PRIO1 MMA_M(af0, 0) PRIO0
        RDFP(8192)
        PRIO1 MMA_P(af0, 0) PRIO0
        RDAO(16384)
        PRIO1 MMA_M(af1, 4) PRIO0
        PRIO1 MMA_P(af1, 4) PRIO0
    }

    // ---- epilogue phase 1: bias + user fold + gate -> padded LDS tile ----
    BAR();   // all waves done reading K-loop LDS; reuse pool as tile [256][TSTRIDE]
    {
        int gc0 = nt * 128 + wc * 32 + r15;
        int gc1 = gc0 + 16;
        int bix = mt >> 1;
        size_t ub = ((size_t)a * NB + bix) * ND;
        float bmv0 = bm[a * ND + gc0] + uM[ub + gc0];
        float bmv1 = bm[a * ND + gc1] + uM[ub + gc1];
        float bpv0 = bp[a * ND + gc0] + uP[ub + gc0];
        float bpv1 = bp[a * ND + gc1] + uP[ub + gc1];
        int col0 = wc * 32 + r15;
        #pragma unroll
        for (int i = 0; i < 8; ++i) {
            int row0 = wr * 128 + i * 16 + g * 4;
            #pragma unroll
            for (int jj = 0; jj < 4; ++jj) {
                float m0 = accM[i][0][jj] + bmv0;
                float p0 = accP[i][0][jj] + bpv0;
                float v0 = p0 / (1.0f + __expf(-m0));
                float m1 = accM[i][1][jj] + bmv1;
                float p1 = accP[i][1][jj] + bpv1;
                float v1 = p1 / (1.0f + __expf(-m1));
                smem[(row0 + jj) * TSTRIDE + col0]      = f2b(v0);
                smem[(row0 + jj) * TSTRIDE + col0 + 16] = f2b(v1);
            }
        }
    }
    BAR();
    // ---- epilogue phase 2: coalesced item store + fused score partials ----
    {
        #pragma unroll
        for (int q = 0; q < 8; ++q) {
            int cid = q * 512 + tid;            // 256 rows x 16 chunks
            int row_l = cid >> 4;
            int c8 = (cid & 15) << 3;
            u16x8 tv = *(const u16x8*)&smem[row_l * TSTRIDE + c8];
            int rowg = mt * 256 + row_l;
            int a2 = rowg & 7;
            int colg8 = nt * 128 + c8;
            f32x4 w0 = *(const f32x4*)&asp[a2 * ND + colg8];
            f32x4 w1 = *(const f32x4*)&asp[a2 * ND + colg8 + 4];
            float s = b2f(tv[0]) * w0[0] + b2f(tv[1]) * w0[1]
                    + b2f(tv[2]) * w0[2] + b2f(tv[3]) * w0[3]
                    + b2f(tv[4]) * w1[0] + b2f(tv[5]) * w1[1]
                    + b2f(tv[6]) * w1[2] + b2f(tv[7]) * w1[3];
            *(u16x8*)(item + ((size_t)al * MROWS + rowg) * ND + colg8) = tv;
            s += __shfl_xor(s, 1);
            s += __shfl_xor(s, 2);
            s += __shfl_xor(s, 4);
            s += __shfl_xor(s, 8);
            if ((tid & 15) == 0)
                scorep[((size_t)al * MROWS + rowg) * 4 + nt] = s;
        }
    }
}

// ---------------- kernel 4: softmax(L) from score partials + weighted sum ----------------
__global__ __launch_bounds__(512) void attn_out_k(
    const u16* __restrict__ item, const float* __restrict__ scorep,
    float* __restrict__ out, int b0) {
    __shared__ float attn[512];
    __shared__ float red[4][512];
    int t = threadIdx.x;
    int bl = blockIdx.x >> 3;
    int ap = blockIdx.x & 7;
    int bg = b0 + bl;

    size_t R = (size_t)bl * 4096 + (size_t)t * 8 + ap;
    f32x4 q = *(const f32x4*)(scorep + R * 4);
    float s = (q[0] + q[1]) + (q[2] + q[3]);

    red[0][t] = s;
    __syncthreads();
    for (int off = 256; off > 0; off >>= 1) {
        if (t < off) red[0][t] = fmaxf(red[0][t], red[0][t + off]);
        __syncthreads();
    }
    float mx = red[0][0];
    __syncthreads();
    float p = __expf(s - mx);
    red[0][t] = p;
    __syncthreads();
    for (int off = 256; off > 0; off >>= 1) {
        if (t < off) red[0][t] += red[0][t + off];
        __syncthreads();
    }
    float inv = 1.0f / red[0][0];
    attn[t] = p * inv;
    __syncthreads();

    // weighted sum: 4 l'-groups x 128 d-threads (4 d each), single item pass
    int gq = t >> 7, u = t & 127;
    float a0v = 0.f, a1v = 0.f, a2v = 0.f, a3v = 0.f;
    const u16* base2 = item + ((size_t)bl * 4096 + ap) * ND + 4 * u;
    for (int l = gq; l < 512; l += 4) {
        float wv = attn[l];
        u16x4 v = *(const u16x4*)(base2 + (size_t)l * 8 * ND);
        a0v += wv * b2f(v[0]); a1v += wv * b2f(v[1]);
        a2v += wv * b2f(v[2]); a3v += wv * b2f(v[3]);
    }
    red[gq][4 * u + 0] = a0v; red[gq][4 * u + 1] = a1v;
    red[gq][4 * u + 2] = a2v; red[gq][4 * u + 3] = a3v;
    __syncthreads();
    float o = red[0][t] + red[1][t] + red[2][t] + red[3][t];
    out[((size_t)bg * NA + ap) * ND + t] = o;
}

// ---------------- launcher ----------------
extern "C" void kernel_launch(void* const* d_in, const int* in_sizes, int n_in,
                              void* d_out, int out_size, void* d_ws, size_t ws_size,
                              hipStream_t stream) {
    const float* H   = (const float*)d_in[0];
    const float* U   = (const float*)d_in[1];
    const float* asp = (const float*)d_in[2];
    const float* Wmf = (const float*)d_in[3];
    const float* bmf = (const float*)d_in[4];
    const float* Wpf = (const float*)d_in[5];
    const float* bpf = (const float*)d_in[6];
    float* out = (float*)d_out;

    char* ws = (char*)d_ws;
    const size_t BT_BYTES = (size_t)MROWS * KH * 2;            // 32 MB
    const size_t WT_BYTES = (size_t)NA * ND * KH * 2;          // 4 MB each
    const size_t U_BYTES  = (size_t)NA * NB * ND * 4;          // 1 MB each
    u16*   Bt = (u16*)(ws);
    u16*   Wm = (u16*)(ws + BT_BYTES);
    u16*   Wp = (u16*)(ws + BT_BYTES + WT_BYTES);
    float* uM = (float*)(ws + BT_BYTES + 2 * WT_BYTES);
    float* uP = (float*)(ws + BT_BYTES + 2 * WT_BYTES + U_BYTES);
    size_t fixed = BT_BYTES + 2 * WT_BYTES + 2 * U_BYTES;      // 42 MB
    const size_t ITEM_PER_ASPECT  = (size_t)MROWS * ND * 2;    // 32 MB
    const size_t SCORE_PER_ASPECT = (size_t)MROWS * 4 * 4;     // 512 KB
    size_t avail = (ws_size > fixed) ? (ws_size - fixed) : 0;
    int na = (int)(avail / (ITEM_PER_ASPECT + SCORE_PER_ASPECT));
    if (na > NA) na = NA;
    if (na < 1) na = 1;
    int log2na = 0;
    while ((2 << log2na) <= na) ++log2na;
    na = 1 << log2na;
    u16*   item   = (u16*)(ws + fixed);
    float* scorep = (float*)(ws + fixed + (size_t)na * ITEM_PER_ASPECT);

    build_batch<<<4096, 256, 0, stream>>>(H, Bt);
    build_wt<<<2048, 256, 0, stream>>>(Wmf, Wpf, Wm, Wp);
    user_mm<<<128, 256, 0, stream>>>(U, Wmf, Wpf, uM, uP);

    for (int a0 = 0; a0 < NA; a0 += na) {
        int n = (na < NA - a0) ? na : (NA - a0);
        gemm8_k<<<n * 512, 512, 0, stream>>>(Bt, Wm, Wp, bmf, bpf, uM, uP, asp,
                                             item, scorep, a0, log2na, n * 512);
        attn_out_k<<<n * 64, 512, 0, stream>>>(item, scorep, out, a0 * 8);
    }
}

// Round 11
// 520.507 us; speedup vs baseline: 1.4391x; 1.0946x over previous
//
#include <hip/hip_runtime.h>
#include <hip/hip_bf16.h>

// ---------------- types ----------------
typedef unsigned short u16;
typedef u16   u16x4 __attribute__((ext_vector_type(4)));
typedef u16   u16x8 __attribute__((ext_vector_type(8)));
typedef short s16x8 __attribute__((ext_vector_type(8)));
typedef float f32x4 __attribute__((ext_vector_type(4)));

// Problem constants
#define NB   64
#define NL   512
#define ND   512
#define NA   8
#define K2   1024        // 2*D (original concat K)
#define KH   512         // GEMM K after user-split (H part only)
#define MROWS 32768      // B*L

__device__ __forceinline__ float b2f(u16 u) {
    unsigned int x = ((unsigned int)u) << 16;
    return __uint_as_float(x);
}
__device__ __forceinline__ u16 f2b(float f) {
    unsigned int x = __float_as_uint(f);
    unsigned int r = (x + 0x7fffu + ((x >> 16) & 1u)) >> 16;
    return (u16)r;
}

// permuted column position for original k within a 64-col K-block (16x16x32 frag)
__device__ __forceinline__ int permc(int k) {
    int ks  = k >> 6;
    int kr  = k & 63;
    int kk  = kr >> 5;
    int k32 = kr & 31;
    int h   = k32 >> 4;
    int rem = k32 & 15;
    int g   = rem >> 2;
    int e0  = rem & 3;
    return ks * 64 + kk * 32 + g * 8 + h * 4 + e0;
}

__device__ __forceinline__ void gload16(const u16* g, u16* l) {
    __builtin_amdgcn_global_load_lds(
        (const __attribute__((address_space(1))) unsigned int*)g,
        (__attribute__((address_space(3))) unsigned int*)l, 16, 0, 0);
}

// ---------------- kernel 1: build permuted bf16 H-matrix [32768][512] ----------------
__global__ void build_batch(const float* __restrict__ H, u16* __restrict__ Bt) {
    size_t stride = (size_t)gridDim.x * blockDim.x;
    for (size_t idx = (size_t)blockIdx.x * blockDim.x + threadIdx.x;
         idx < (size_t)MROWS * 128; idx += stride) {
        int r  = (int)(idx >> 7);
        int c  = ((int)idx & 127) << 2;       // permuted col (multiple of 4)
        int ks = c >> 6;
        int w64 = c & 63;
        int cq = w64 >> 3;
        int h  = (w64 >> 2) & 1;
        int kbase = ks * 64 + (cq >> 2) * 32 + (cq & 3) * 4 + h * 16;  // < 512
        f32x4 v = *(const f32x4*)(H + (size_t)r * ND + kbase);
        u16x4 o;
        o[0] = f2b(v[0]); o[1] = f2b(v[1]); o[2] = f2b(v[2]); o[3] = f2b(v[3]);
        *(u16x4*)(Bt + (size_t)r * KH + c) = o;
    }
}

// ---------------- kernel 2: W top half (k<512) -> Wt (A,512,512) bf16 permuted ----------------
__global__ void build_wt(const float* __restrict__ Wmf, const float* __restrict__ Wpf,
                         u16* __restrict__ Wm, u16* __restrict__ Wp) {
    __shared__ float ld[32][65];
    int bid = blockIdx.x;
    int kt  = bid & 15;            // 16 x 32 = 512 k
    int dt  = (bid >> 4) & 7;
    int a   = (bid >> 7) & 7;
    int mat = bid >> 10;
    const float* W = mat ? Wpf : Wmf;
    u16* Wt = mat ? Wp : Wm;
    int k0 = kt * 32, d0 = dt * 64;
    int t = threadIdx.x;
    #pragma unroll
    for (int it = 0; it < 8; ++it) {
        int lin = it * 256 + t;
        int i = lin >> 6, j = lin & 63;
        ld[i][j] = W[((size_t)a * K2 + k0 + i) * ND + d0 + j];
    }
    __syncthreads();
    #pragma unroll
    for (int it = 0; it < 8; ++it) {
        int lin = it * 256 + t;
        int dl = lin >> 5, kl = lin & 31;
        int k = k0 + kl;
        Wt[((size_t)a * ND + d0 + dl) * KH + permc(k)] = f2b(ld[kl][dl]);
    }
}

// ---------------- kernel 2b: user term  uX[a][b][col] = sum_k U[b][k] * W[a][512+k][col] ----------------
__global__ __launch_bounds__(256) void user_mm(
    const float* __restrict__ U, const float* __restrict__ Wmf,
    const float* __restrict__ Wpf, float* __restrict__ uM, float* __restrict__ uP) {
    __shared__ float wl[64][64];
    __shared__ float ul[64][64];
    int bid = blockIdx.x;
    int a   = bid & 7;
    int mat = (bid >> 3) & 1;
    int cg  = bid >> 4;
    int col0 = cg * 64;
    const float* W = mat ? Wpf : Wmf;
    float* uX = mat ? uP : uM;
    int t = threadIdx.x;
    int c = t & 63, bq = t >> 6;           // col_local, b-quarter

    float acc[16];
    #pragma unroll
    for (int i = 0; i < 16; ++i) acc[i] = 0.0f;

    for (int kt = 0; kt < 8; ++kt) {
        int k0 = kt * 64;
        #pragma unroll
        for (int i = 0; i < 16; ++i)
            wl[bq * 16 + i][c] = W[((size_t)a * K2 + 512 + k0 + bq * 16 + i) * ND + col0 + c];
        #pragma unroll
        for (int i = 0; i < 16; ++i) {
            int idx = i * 256 + t;
            ul[idx >> 6][idx & 63] = U[(size_t)(idx >> 6) * ND + k0 + (idx & 63)];
        }
        __syncthreads();
        #pragma unroll
        for (int b2 = 0; b2 < 16; ++b2) {
            float s = 0.0f;
            #pragma unroll
            for (int k = 0; k < 64; ++k)
                s += ul[bq * 16 + b2][k] * wl[k][c];
            acc[b2] += s;
        }
        __syncthreads();
    }
    #pragma unroll
    for (int b2 = 0; b2 < 16; ++b2)
        uX[((size_t)a * NB + bq * 16 + b2) * ND + col0 + c] = acc[b2];
}

// ---------------- kernel 3: 128x128-tile K=512 dual GEMM, 2 blocks/CU ----------------
// BM=128, BN=128, BK=32, 8 waves (2M x 4N, wave 64x32), double-buffered LDS 48KB.
#define BAR()    do { __builtin_amdgcn_sched_barrier(0); \
                      __builtin_amdgcn_s_barrier(); \
                      __builtin_amdgcn_sched_barrier(0); } while (0)
#define WAITV(n) do { asm volatile("s_waitcnt vmcnt(" #n ")" ::: "memory"); \
                      __builtin_amdgcn_sched_barrier(0); } while (0)
#define PRIO1    __builtin_amdgcn_s_setprio(1);
#define PRIO0    __builtin_amdgcn_s_setprio(0);

// LDS pool (u16 units): A 2x4096 @0, Bm 2x4096 @8192, Bp 2x4096 @16384.
#define A_OFF  0
#define M_OFF  8192
#define P_OFF  16384
#define TST    136      // epilogue tile row stride (u16), 128x136 = 34KB

#define RDA(B_) { _Pragma("unroll") for (int i_ = 0; i_ < 4; ++i_) \
    af[i_] = *(const s16x8*)(pA + (B_) * 4096 + i_ * 512); }
#define RDM(B_) { fm[0] = *(const s16x8*)(pM + (B_) * 4096); \
                  fm[1] = *(const s16x8*)(pM + (B_) * 4096 + 512); }
#define RDP(B_) { fp[0] = *(const s16x8*)(pP + (B_) * 4096); \
                  fp[1] = *(const s16x8*)(pP + (B_) * 4096 + 512); }

#define MMAM { _Pragma("unroll") for (int i_ = 0; i_ < 4; ++i_) \
    _Pragma("unroll") for (int j_ = 0; j_ < 2; ++j_) \
        accM[i_][j_] = __builtin_amdgcn_mfma_f32_16x16x32_bf16( \
            af[i_], fm[j_], accM[i_][j_], 0, 0, 0); }
#define MMAP { _Pragma("unroll") for (int i_ = 0; i_ < 4; ++i_) \
    _Pragma("unroll") for (int j_ = 0; j_ < 2; ++j_) \
        accP[i_][j_] = __builtin_amdgcn_mfma_f32_16x16x32_bf16( \
            af[i_], fp[j_], accP[i_][j_], 0, 0, 0); }

#define STEP(CUR, T) { \
    stA((CUR) ^ 1, (T) + 1); stM((CUR) ^ 1, (T) + 1); stP((CUR) ^ 1, (T) + 1); \
    RDA(CUR) RDM(CUR) \
    PRIO1 MMAM PRIO0 \
    RDP(CUR) \
    PRIO1 MMAP PRIO0 \
    WAITV(0); BAR(); }

__global__ __launch_bounds__(512, 4) void gemm8_k(
    const u16* __restrict__ Bt, const u16* __restrict__ Wm, const u16* __restrict__ Wp,
    const float* __restrict__ bm, const float* __restrict__ bp,
    const float* __restrict__ uM, const float* __restrict__ uP,
    const float* __restrict__ asp,
    u16* __restrict__ item, float* __restrict__ scorep,
    int a0, int log2na, int nwg) {
    __shared__ u16 smem[24576];         // 48 KB pool

    int bid = blockIdx.x;
    int chunk = nwg >> 3;                       // XCD-aware swizzle (nwg % 8 == 0)
    int b = (bid & 7) * chunk + (bid >> 3);
    int nt = b & 3;                             // N-tile fastest: share A panel
    int al = (b >> 2) & ((1 << log2na) - 1);
    int mt = b >> (2 + log2na);                 // 0..255
    int a  = a0 + al;

    int tid = threadIdx.x;
    int lane = tid & 63;
    int w  = tid >> 6;        // 0..7
    int wr = w >> 2;          // 0..1  (M half: 64 rows)
    int wc = w & 3;           // 0..3  (N quarter: 32 cols)
    int g = lane >> 4, r15 = lane & 15;

    const u16* Abase = Bt + (size_t)(mt * 128) * KH;
    const u16* Mbase = Wm + ((size_t)a * ND + nt * 128) * KH;
    const u16* Pbase = Wp + ((size_t)a * ND + nt * 128) * KH;

    // hoisted swizzled read bases: slot = g ^ (row&3) ^ ((row>>2)&3), loop-invariant
    int ps = (g ^ (r15 & 3) ^ ((r15 >> 2) & 3)) << 3;
    const u16* pA = &smem[A_OFF + (wr * 64 + r15) * 32 + ps];
    const u16* pM = &smem[M_OFF + (wc * 32 + r15) * 32 + ps];
    const u16* pP = &smem[P_OFF + (wc * 32 + r15) * 32 + ps];

    // staging: one gload16 round covers a full 128x32 tile (512 thr x 16B)
    int srow = tid >> 2, sq = tid & 3;
    int qsw = (sq ^ (srow & 3) ^ ((srow >> 2) & 3)) << 3;
    auto stA = [&](int buf, int ks) {
        gload16(Abase + (size_t)srow * KH + ks * 32 + qsw,
                &smem[A_OFF + buf * 4096 + srow * 32 + sq * 8]);
    };
    auto stM = [&](int buf, int ks) {
        gload16(Mbase + (size_t)srow * KH + ks * 32 + qsw,
                &smem[M_OFF + buf * 4096 + srow * 32 + sq * 8]);
    };
    auto stP = [&](int buf, int ks) {
        gload16(Pbase + (size_t)srow * KH + ks * 32 + qsw,
                &smem[P_OFF + buf * 4096 + srow * 32 + sq * 8]);
    };

    f32x4 accM[4][2], accP[4][2];
    #pragma unroll
    for (int i = 0; i < 4; ++i)
        #pragma unroll
        for (int j = 0; j < 2; ++j) { accM[i][j] = 0.0f; accP[i][j] = 0.0f; }

    s16x8 af[4], fm[2], fp[2];

    // ---- prologue: stage K0 into buf0 ----
    stA(0, 0); stM(0, 0); stP(0, 0);
    WAITV(0); BAR();

    // ---- steady loop: K-steps 0..14 (16 total, BK=32) ----
    for (int t = 0; t < 14; t += 2) {
        STEP(0, t)
        STEP(1, t + 1)
    }
    STEP(0, 14)     // stages ks=15 into buf1

    // ---- K-step 15: compute only (cur = 1) ----
    {
        RDA(1) RDM(1)
        PRIO1 MMAM PRIO0
        RDP(1)
        PRIO1 MMAP PRIO0
    }

    // ---- epilogue phase 1: bias + user fold + fast sigmoid -> LDS tile ----
    BAR();   // all waves done reading K-loop LDS; reuse pool as tile [128][TST]
    {
        int gc0 = nt * 128 + wc * 32 + r15;
        int gc1 = gc0 + 16;
        int bix = mt >> 2;                  // 4 blocks of 128 rows per batch
        size_t ub = ((size_t)a * NB + bix) * ND;
        float bmv0 = bm[a * ND + gc0] + uM[ub + gc0];
        float bmv1 = bm[a * ND + gc1] + uM[ub + gc1];
        float bpv0 = bp[a * ND + gc0] + uP[ub + gc0];
        float bpv1 = bp[a * ND + gc1] + uP[ub + gc1];
        int col0 = wc * 32 + r15;
        #pragma unroll
        for (int i = 0; i < 4; ++i) {
            int row0 = wr * 64 + i * 16 + g * 4;
            #pragma unroll
            for (int jj = 0; jj < 4; ++jj) {
                float m0 = accM[i][0][jj] + bmv0;
                float p0 = accP[i][0][jj] + bpv0;
                float v0 = p0 * __builtin_amdgcn_rcpf(1.0f + __expf(-m0));
                float m1 = accM[i][1][jj] + bmv1;
                float p1 = accP[i][1][jj] + bpv1;
                float v1 = p1 * __builtin_amdgcn_rcpf(1.0f + __expf(-m1));
                unsigned int pk;
                asm("v_cvt_pk_bf16_f32 %0, %1, %2" : "=v"(pk) : "v"(v0), "v"(v1));
                smem[(row0 + jj) * TST + col0]      = (u16)pk;
                smem[(row0 + jj) * TST + col0 + 16] = (u16)(pk >> 16);
            }
        }
    }
    BAR();
    // ---- epilogue phase 2: coalesced item store + fused score partials ----
    {
        #pragma unroll
        for (int q = 0; q < 4; ++q) {
            int cid = q * 512 + tid;            // 128 rows x 16 chunks
            int row_l = cid >> 4;
            int c8 = (cid & 15) << 3;
            u16x8 tv = *(const u16x8*)&smem[row_l * TST + c8];
            int rowg = mt * 128 + row_l;
            int a2 = rowg & 7;
            int colg8 = nt * 128 + c8;
            f32x4 w0 = *(const f32x4*)&asp[a2 * ND + colg8];
            f32x4 w1 = *(const f32x4*)&asp[a2 * ND + colg8 + 4];
            float s = b2f(tv[0]) * w0[0] + b2f(tv[1]) * w0[1]
                    + b2f(tv[2]) * w0[2] + b2f(tv[3]) * w0[3]
                    + b2f(tv[4]) * w1[0] + b2f(tv[5]) * w1[1]
                    + b2f(tv[6]) * w1[2] + b2f(tv[7]) * w1[3];
            *(u16x8*)(item + ((size_t)al * MROWS + rowg) * ND + colg8) = tv;
            s += __shfl_xor(s, 1);
            s += __shfl_xor(s, 2);
            s += __shfl_xor(s, 4);
            s += __shfl_xor(s, 8);
            if ((tid & 15) == 0)
                scorep[((size_t)al * MROWS + rowg) * 4 + nt] = s;
        }
    }
}

// ---------------- kernel 4: softmax(L) from score partials + weighted sum ----------------
__global__ __launch_bounds__(512) void attn_out_k(
    const u16* __restrict__ item, const float* __restrict__ scorep,
    float* __restrict__ out, int b0) {
    __shared__ float attn[512];
    __shared__ float red[4][512];
    int t = threadIdx.x;
    int bl = blockIdx.x >> 3;
    int ap = blockIdx.x & 7;
    int bg = b0 + bl;

    size_t R = (size_t)bl * 4096 + (size_t)t * 8 + ap;
    f32x4 q = *(const f32x4*)(scorep + R * 4);
    float s = (q[0] + q[1]) + (q[2] + q[3]);

    red[0][t] = s;
    __syncthreads();
    for (int off = 256; off > 0; off >>= 1) {
        if (t < off) red[0][t] = fmaxf(red[0][t], red[0][t + off]);
        __syncthreads();
    }
    float mx = red[0][0];
    __syncthreads();
    float p = __expf(s - mx);
    red[0][t] = p;
    __syncthreads();
    for (int off = 256; off > 0; off >>= 1) {
        if (t < off) red[0][t] += red[0][t + off];
        __syncthreads();
    }
    float inv = 1.0f / red[0][0];
    attn[t] = p * inv;
    __syncthreads();

    // weighted sum: 4 l'-groups x 128 d-threads (4 d each), single item pass
    int gq = t >> 7, u = t & 127;
    float a0v = 0.f, a1v = 0.f, a2v = 0.f, a3v = 0.f;
    const u16* base2 = item + ((size_t)bl * 4096 + ap) * ND + 4 * u;
    for (int l = gq; l < 512; l += 4) {
        float wv = attn[l];
        u16x4 v = *(const u16x4*)(base2 + (size_t)l * 8 * ND);
        a0v += wv * b2f(v[0]); a1v += wv * b2f(v[1]);
        a2v += wv * b2f(v[2]); a3v += wv * b2f(v[3]);
    }
    red[gq][4 * u + 0] = a0v; red[gq][4 * u + 1] = a1v;
    red[gq][4 * u + 2] = a2v; red[gq][4 * u + 3] = a3v;
    __syncthreads();
    float o = red[0][t] + red[1][t] + red[2][t] + red[3][t];
    out[((size_t)bg * NA + ap) * ND + t] = o;
}

// ---------------- launcher ----------------
extern "C" void kernel_launch(void* const* d_in, const int* in_sizes, int n_in,
                              void* d_out, int out_size, void* d_ws, size_t ws_size,
                              hipStream_t stream) {
    const float* H   = (const float*)d_in[0];
    const float* U   = (const float*)d_in[1];
    const float* asp = (const float*)d_in[2];
    const float* Wmf = (const float*)d_in[3];
    const float* bmf = (const float*)d_in[4];
    const float* Wpf = (const float*)d_in[5];
    const float* bpf = (const float*)d_in[6];
    float* out = (float*)d_out;

    char* ws = (char*)d_ws;
    const size_t BT_BYTES = (size_t)MROWS * KH * 2;            // 32 MB
    const size_t WT_BYTES = (size_t)NA * ND * KH * 2;          // 4 MB each
    const size_t U_BYTES  = (size_t)NA * NB * ND * 4;          // 1 MB each
    u16*   Bt = (u16*)(ws);
    u16*   Wm = (u16*)(ws + BT_BYTES);
    u16*   Wp = (u16*)(ws + BT_BYTES + WT_BYTES);
    float* uM = (float*)(ws + BT_BYTES + 2 * WT_BYTES);
    float* uP = (float*)(ws + BT_BYTES + 2 * WT_BYTES + U_BYTES);
    size_t fixed = BT_BYTES + 2 * WT_BYTES + 2 * U_BYTES;      // 42 MB
    const size_t ITEM_PER_ASPECT  = (size_t)MROWS * ND * 2;    // 32 MB
    const size_t SCORE_PER_ASPECT = (size_t)MROWS * 4 * 4;     // 512 KB
    size_t avail = (ws_size > fixed) ? (ws_size - fixed) : 0;
    int na = (int)(avail / (ITEM_PER_ASPECT + SCORE_PER_ASPECT));
    if (na > NA) na = NA;
    if (na < 1) na = 1;
    int log2na = 0;
    while ((2 << log2na) <= na) ++log2na;
    na = 1 << log2na;
    u16*   item   = (u16*)(ws + fixed);
    float* scorep = (float*)(ws + fixed + (size_t)na * ITEM_PER_ASPECT);

    build_batch<<<4096, 256, 0, stream>>>(H, Bt);
    build_wt<<<2048, 256, 0, stream>>>(Wmf, Wpf, Wm, Wp);
    user_mm<<<128, 256, 0, stream>>>(U, Wmf, Wpf, uM, uP);

    for (int a0 = 0; a0 < NA; a0 += na) {
        int n = (na < NA - a0) ? na : (NA - a0);
        gemm8_k<<<n * 1024, 512, 0, stream>>>(Bt, Wm, Wp, bmf, bpf, uM, uP, asp,
                                              item, scorep, a0, log2na, n * 1024);
        attn_out_k<<<n * 64, 512, 0, stream>>>(item, scorep, out, a0 * 8);
    }
}